// Round 7
// baseline (529.888 us; speedup 1.0000x reference)
//
#include <hip/hip_runtime.h>

#define NPTS 4096
#define NCH  64
#define NB   8
#define KNN  16
#define NSPLIT 4

typedef _Float16 h8 __attribute__((ext_vector_type(8)));
typedef float    f4 __attribute__((ext_vector_type(4)));
typedef unsigned long long ull;

// ---------------- K1: xm = 4096 - sum_c x^2 (f64) + transposed f16 hi/lo ------
__global__ __launch_bounds__(256) void k_prep(const float* __restrict__ x,
                                              double* __restrict__ xm,
                                              _Float16* __restrict__ xhT,
                                              _Float16* __restrict__ xlT) {
    __shared__ float tile[64 * 65];
    const int tid = threadIdx.x;
    const int blk = blockIdx.x;
    const int b = blk >> 6, n0 = (blk & 63) << 6;
    const float* xb = x + (size_t)b * NCH * NPTS;
    for (int i = tid; i < 4096; i += 256) {
        int c = i >> 6, nn = i & 63;
        tile[c * 65 + nn] = xb[(size_t)c * NPTS + n0 + nn];
    }
    __syncthreads();
    if (tid < 64) {
        double a = 0.0;
        #pragma unroll
        for (int c = 0; c < 64; ++c) {
            double v = (double)tile[c * 65 + tid];
            a = fma(v, v, a);
        }
        xm[((size_t)b << 12) + n0 + tid] = 4096.0 - a;
    }
    for (int i = tid; i < 4096; i += 256) {
        int n = i >> 6, c = i & 63;
        float v = tile[c * 65 + n];
        _Float16 h = (_Float16)v;
        _Float16 l = (_Float16)(v - (float)h);
        size_t o = (((size_t)b << 12) + n0 + n) * 64 + c;
        xhT[o] = h;
        xlT[o] = l;
    }
}

// ---------------- K2: KNN partial top-16, f16-split MFMA, in-register scan ----
// blockIdx.z = candidate-tile split (16 tiles = 1024 candidates per query).
// Lane (g,j) of wave w: query q0+16w+j, candidates m = m0+16mt+4g+r.
// Per-query 4-scanner merge via __shfl tree (all 4 scanners in one wave).
// Packed per-split top-16 written to part[(split*16+slot)][query] (slot-major).
__global__ __launch_bounds__(256) void k_knn(const float* __restrict__ x,
                                             const double* __restrict__ xm,
                                             const _Float16* __restrict__ xhT,
                                             const _Float16* __restrict__ xlT,
                                             double* __restrict__ part) {
    __shared__ int okflag;
    const int tid = threadIdx.x, lane = tid & 63, w = tid >> 6;
    const int g = lane >> 4, j = lane & 15;
    const int b = blockIdx.y, q0 = blockIdx.x * 64;
    const int split = blockIdx.z;
    const int t0 = split * 16;
    const size_t bbase = (size_t)b << 12;
    const _Float16* Hb = xhT + bbase * 64;
    const _Float16* Lb = xlT + bbase * 64;
    const double*  xmb = xm + bbase;

    const int qcol = q0 + 16 * w + j;
    h8 Bh[2], Bl[2];
    #pragma unroll
    for (int kk = 0; kk < 2; ++kk) {
        size_t o = (size_t)qcol * 64 + kk * 32 + 8 * g;
        Bh[kk] = *(const h8*)(Hb + o);
        Bl[kk] = *(const h8*)(Lb + o);
    }

    if (tid == 0) okflag = 1;
    __syncthreads();

    // ---- asymmetric layout probe (shift-by-1 queries as A) ----
    {
        const int rsh = q0 + 16 * w + ((j + 1) & 15);
        f4 acc = {0.f, 0.f, 0.f, 0.f};
        #pragma unroll
        for (int kk = 0; kk < 2; ++kk) {
            size_t o = (size_t)rsh * 64 + kk * 32 + 8 * g;
            h8 Ah = *(const h8*)(Hb + o);
            h8 Al = *(const h8*)(Lb + o);
            acc = __builtin_amdgcn_mfma_f32_16x16x32_f16(Ah, Bh[kk], acc, 0, 0, 0);
            acc = __builtin_amdgcn_mfma_f32_16x16x32_f16(Ah, Bl[kk], acc, 0, 0, 0);
            acc = __builtin_amdgcn_mfma_f32_16x16x32_f16(Al, Bh[kk], acc, 0, 0, 0);
        }
        bool bad = false;
        #pragma unroll
        for (int rr = 0; rr < 2; ++rr) {
            const int r = rr ? 3 : 0;
            const int urow = q0 + 16 * w + ((4 * g + r + 1) & 15);
            double tgt = 0.0;
            #pragma unroll 4
            for (int c = 0; c < 64; ++c) {
                double av = (double)(float)Hb[(size_t)urow * 64 + c]
                          + (double)(float)Lb[(size_t)urow * 64 + c];
                double bv = (double)(float)Hb[(size_t)qcol * 64 + c]
                          + (double)(float)Lb[(size_t)qcol * 64 + c];
                tgt = fma(av, bv, tgt);
            }
            double got = (double)acc[r];
            if (fabs(got - tgt) > 1e-3 * (1.0 + fabs(tgt))) bad = true;
        }
        if (__any(bad ? 1 : 0)) okflag = 0;   // benign same-value race
    }
    __syncthreads();
    const bool mfma_ok = (okflag != 0);

    double s[16];
    #pragma unroll
    for (int i = 0; i < 16; ++i) s[i] = 0.0;

    if (mfma_ok) {
        for (int t = t0; t < t0 + 16; ++t) {
            const int m0 = t * 64;
            #pragma unroll
            for (int mt = 0; mt < 4; ++mt) {
                const int arow = m0 + 16 * mt + j;
                f4 acc = {0.f, 0.f, 0.f, 0.f};
                #pragma unroll
                for (int kk = 0; kk < 2; ++kk) {
                    size_t o = (size_t)arow * 64 + kk * 32 + 8 * g;
                    h8 Ah = *(const h8*)(Hb + o);
                    h8 Al = *(const h8*)(Lb + o);
                    acc = __builtin_amdgcn_mfma_f32_16x16x32_f16(Ah, Bh[kk], acc, 0, 0, 0);
                    acc = __builtin_amdgcn_mfma_f32_16x16x32_f16(Ah, Bl[kk], acc, 0, 0, 0);
                    acc = __builtin_amdgcn_mfma_f32_16x16x32_f16(Al, Bh[kk], acc, 0, 0, 0);
                }
                const int mbase = m0 + 16 * mt + 4 * g;
                #pragma unroll
                for (int r = 0; r < 4; ++r) {
                    const int m = mbase + r;
                    double pv = fma(2.0, (double)acc[r], xmb[m]);   // 2*dot - xx + 4096
                    ull bits = (((ull)__double_as_longlong(pv)) & 0xFFFFFFFFFFFFF000ULL)
                             | (ull)(4095 - m);
                    double v = __longlong_as_double((long long)bits);
                    #pragma unroll
                    for (int i = 0; i < 15; ++i) s[i] = fmin(s[i + 1], fmax(v, s[i]));
                    s[15] = fmax(v, s[15]);
                }
            }
        }
    } else {
        // insurance fallback: exact f64 dots straight from global x (slow path)
        const float* xb = x + (size_t)b * NCH * NPTS;
        for (int t = t0; t < t0 + 16; ++t) {
            const int m0 = t * 64;
            #pragma unroll
            for (int mt = 0; mt < 4; ++mt) {
                #pragma unroll
                for (int r = 0; r < 4; ++r) {
                    const int m = m0 + 16 * mt + 4 * g + r;
                    double dot = 0.0;
                    for (int c = 0; c < 64; ++c)
                        dot = fma((double)xb[(size_t)c * NPTS + m],
                                  (double)xb[(size_t)c * NPTS + qcol], dot);
                    double pv = fma(2.0, dot, xmb[m]);
                    ull bits = (((ull)__double_as_longlong(pv)) & 0xFFFFFFFFFFFFF000ULL)
                             | (ull)(4095 - m);
                    double v = __longlong_as_double((long long)bits);
                    #pragma unroll
                    for (int i = 0; i < 15; ++i) s[i] = fmin(s[i + 1], fmax(v, s[i]));
                    s[15] = fmax(v, s[15]);
                }
            }
        }
    }

    // ---- in-wave 4-scanner merge: g0<-g2, g1<-g3, then g0<-g1 ----
    #pragma unroll
    for (int i = 0; i < 16; ++i) {
        double v = __shfl(s[i], (lane + 32) & 63, 64);
        if (g < 2) {
            #pragma unroll
            for (int k2 = 0; k2 < 15; ++k2) s[k2] = fmin(s[k2 + 1], fmax(v, s[k2]));
            s[15] = fmax(v, s[15]);
        }
    }
    #pragma unroll
    for (int i = 0; i < 16; ++i) {
        double v = __shfl(s[i], (lane + 16) & 63, 64);
        if (g == 0) {
            #pragma unroll
            for (int k2 = 0; k2 < 15; ++k2) s[k2] = fmin(s[k2 + 1], fmax(v, s[k2]));
            s[15] = fmax(v, s[15]);
        }
    }
    if (g == 0) {
        const size_t qi = bbase + q0 + 16 * w + j;
        #pragma unroll
        for (int i = 0; i < 16; ++i)
            part[(size_t)(split * 16 + i) * (NB * NPTS) + qi] = s[i];
    }
}

// ---------------- K2b: merge NSPLIT partial lists -> final idx ----------------
__global__ __launch_bounds__(256) void k_kmerge(const double* __restrict__ part,
                                                int* __restrict__ idx_out) {
    const int qi = blockIdx.x * 256 + threadIdx.x;   // [0, 32768)
    double tb[16];
    #pragma unroll
    for (int i = 0; i < 16; ++i) tb[i] = 0.0;
    for (int sp = 0; sp < NSPLIT; ++sp) {
        #pragma unroll
        for (int i = 0; i < 16; ++i) {
            double v = part[(size_t)(sp * 16 + i) * (NB * NPTS) + qi];
            #pragma unroll
            for (int k2 = 0; k2 < 15; ++k2) tb[k2] = fmin(tb[k2 + 1], fmax(v, tb[k2]));
            tb[15] = fmax(v, tb[15]);
        }
    }
    int* op = idx_out + (size_t)qi * KNN;
    #pragma unroll
    for (int i = 0; i < 16; ++i) {
        int code = (int)((ull)__double_as_longlong(tb[i]) & 0xFFFULL);
        op[i] = 4095 - code;
    }
}

// ---------------- K3: P = W1 * x ; Q = (W2 - W1) * x  (both [b][n][o]) --------
__global__ __launch_bounds__(256) void k_pq(const float* __restrict__ x,
                                            const float* __restrict__ W,
                                            float* __restrict__ P,
                                            float* __restrict__ Q) {
    __shared__ __align__(16) float sX[4096];
    __shared__ __align__(16) float sWt[8192];
    const int tid = threadIdx.x;
    const int g0  = blockIdx.x * 64;
    const int b   = g0 >> 12;
    const int n0  = g0 & 4095;
    const float* xb = x + (size_t)b * NCH * NPTS;

    for (int i = tid; i < 8192; i += 256) {
        int c = i >> 7, oc = i & 127;
        float wv;
        if (oc < 64) wv = W[oc * 128 + c];
        else { int o = oc - 64; wv = W[o * 128 + 64 + c] - W[o * 128 + c]; }
        sWt[c * 128 + oc] = wv;
    }
    for (int i = tid; i < 4096; i += 256) {
        int c = i >> 6, m = i & 63;
        sX[i] = xb[(size_t)c * NPTS + n0 + m];
    }
    __syncthreads();

    const int ty = tid >> 4, tx = tid & 15;
    float aP[4][4], aQ[4][4];
    #pragma unroll
    for (int i = 0; i < 4; ++i)
        #pragma unroll
        for (int jj = 0; jj < 4; ++jj) { aP[i][jj] = 0.f; aQ[i][jj] = 0.f; }

    const float4* a4 = (const float4*)sX + ty;
    const float4* p4 = (const float4*)sWt + tx;
    const float4* q4 = (const float4*)sWt + 16 + tx;
    #pragma unroll 8
    for (int kk = 0; kk < 64; ++kk) {
        float4 a  = a4[kk * 16];
        float4 wp = p4[kk * 32];
        float4 wq = q4[kk * 32];
        aP[0][0] = fmaf(a.x, wp.x, aP[0][0]); aP[0][1] = fmaf(a.x, wp.y, aP[0][1]);
        aP[0][2] = fmaf(a.x, wp.z, aP[0][2]); aP[0][3] = fmaf(a.x, wp.w, aP[0][3]);
        aP[1][0] = fmaf(a.y, wp.x, aP[1][0]); aP[1][1] = fmaf(a.y, wp.y, aP[1][1]);
        aP[1][2] = fmaf(a.y, wp.z, aP[1][2]); aP[1][3] = fmaf(a.y, wp.w, aP[1][3]);
        aP[2][0] = fmaf(a.z, wp.x, aP[2][0]); aP[2][1] = fmaf(a.z, wp.y, aP[2][1]);
        aP[2][2] = fmaf(a.z, wp.z, aP[2][2]); aP[2][3] = fmaf(a.z, wp.w, aP[2][3]);
        aP[3][0] = fmaf(a.w, wp.x, aP[3][0]); aP[3][1] = fmaf(a.w, wp.y, aP[3][1]);
        aP[3][2] = fmaf(a.w, wp.z, aP[3][2]); aP[3][3] = fmaf(a.w, wp.w, aP[3][3]);
        aQ[0][0] = fmaf(a.x, wq.x, aQ[0][0]); aQ[0][1] = fmaf(a.x, wq.y, aQ[0][1]);
        aQ[0][2] = fmaf(a.x, wq.z, aQ[0][2]); aQ[0][3] = fmaf(a.x, wq.w, aQ[0][3]);
        aQ[1][0] = fmaf(a.y, wq.x, aQ[1][0]); aQ[1][1] = fmaf(a.y, wq.y, aQ[1][1]);
        aQ[1][2] = fmaf(a.y, wq.z, aQ[1][2]); aQ[1][3] = fmaf(a.y, wq.w, aQ[1][3]);
        aQ[2][0] = fmaf(a.z, wq.x, aQ[2][0]); aQ[2][1] = fmaf(a.z, wq.y, aQ[2][1]);
        aQ[2][2] = fmaf(a.z, wq.z, aQ[2][2]); aQ[2][3] = fmaf(a.z, wq.w, aQ[2][3]);
        aQ[3][0] = fmaf(a.w, wq.x, aQ[3][0]); aQ[3][1] = fmaf(a.w, wq.y, aQ[3][1]);
        aQ[3][2] = fmaf(a.w, wq.z, aQ[3][2]); aQ[3][3] = fmaf(a.w, wq.w, aQ[3][3]);
    }
    #pragma unroll
    for (int i = 0; i < 4; ++i) {
        size_t row = (size_t)(g0 + ty * 4 + i) * 64;
        float4 vp; vp.x = aP[i][0]; vp.y = aP[i][1]; vp.z = aP[i][2]; vp.w = aP[i][3];
        float4 vq; vq.x = aQ[i][0]; vq.y = aQ[i][1]; vq.z = aQ[i][2]; vq.w = aQ[i][3];
        ((float4*)(P + row))[tx] = vp;
        ((float4*)(Q + row))[tx] = vq;
    }
}

// ---------------- K4: gather + max/min over k + global sum/sumsq --------------
__global__ __launch_bounds__(256) void k_stats(const float* __restrict__ P,
                                               const float* __restrict__ Q,
                                               const int* __restrict__ idx,
                                               float* __restrict__ Mx,
                                               float* __restrict__ Mn,
                                               float* __restrict__ gsum,
                                               float* __restrict__ gsum2) {
    const int tid = threadIdx.x;
    const int o = tid & 63, ng = tid >> 6;
    const int b = blockIdx.y;
    const int n0 = blockIdx.x * 16;
    const float* Pb = P + (((size_t)b << 12) * 64);
    float ssum = 0.f, ssq = 0.f;
    for (int jj = 0; jj < 4; ++jj) {
        int n = n0 + ng * 4 + jj;
        size_t base = ((size_t)b << 12) + n;
        float qv = Q[base * 64 + o];
        const int* ip = idx + base * 16;
        float vmax = -3.4e38f, vmin = 3.4e38f;
        #pragma unroll
        for (int k = 0; k < 16; ++k) {
            int m = ip[k];
            float v = Pb[(size_t)m * 64 + o] + qv;
            vmax = fmaxf(vmax, v);
            vmin = fminf(vmin, v);
            ssum += v;
            ssq  = fmaf(v, v, ssq);
        }
        Mx[base * 64 + o] = vmax;
        Mn[base * 64 + o] = vmin;
    }
    __shared__ float red[8][64];
    red[ng][o] = ssum;
    red[ng + 4][o] = ssq;
    __syncthreads();
    if (tid < 64) {
        float ss  = red[0][o] + red[1][o] + red[2][o] + red[3][o];
        float ss2 = red[4][o] + red[5][o] + red[6][o] + red[7][o];
        atomicAdd(&gsum[o], ss);
        atomicAdd(&gsum2[o], ss2);
    }
}

// ---------------- K5: BN + LeakyReLU + transpose to [b][o][n] -----------------
__global__ __launch_bounds__(256) void k_final(const float* __restrict__ Mx,
                                               const float* __restrict__ Mn,
                                               const float* __restrict__ gsum,
                                               const float* __restrict__ gsum2,
                                               const float* __restrict__ gamma,
                                               const float* __restrict__ beta,
                                               float* __restrict__ out) {
    __shared__ float tX[64 * 65], tN[64 * 65];
    const int tid = threadIdx.x;
    const int b = blockIdx.y;
    const int n0 = blockIdx.x * 64;
    size_t base = ((size_t)b << 12) + n0;
    for (int i = tid; i < 4096; i += 256) {
        int nl = i >> 6, o = i & 63;
        tX[nl * 65 + o] = Mx[(base + nl) * 64 + o];
        tN[nl * 65 + o] = Mn[(base + nl) * 64 + o];
    }
    __syncthreads();
    const int lane = tid & 63, wv = tid >> 6;
    const float inv = 1.0f / 524288.0f;
    for (int oo = 0; oo < 16; ++oo) {
        int o = wv * 16 + oo;
        float mean = gsum[o] * inv;
        float var  = gsum2[o] * inv - mean * mean;
        float scv  = gamma[o] * rsqrtf(var + 1e-5f);
        float bsv  = beta[o] - mean * scv;
        float M = (scv >= 0.f) ? tX[lane * 65 + o] : tN[lane * 65 + o];
        float v = fmaf(scv, M, bsv);
        out[((size_t)b * 64 + o) * 4096 + n0 + lane] = (v >= 0.f) ? v : 0.2f * v;
    }
}

extern "C" void kernel_launch(void* const* d_in, const int* in_sizes, int n_in,
                              void* d_out, int out_size, void* d_ws, size_t ws_size,
                              hipStream_t stream) {
    const float* x     = (const float*)d_in[0];
    const float* W     = (const float*)d_in[1];
    const float* gamma = (const float*)d_in[2];
    const float* beta  = (const float*)d_in[3];
    float* out = (float*)d_out;

    char* ws = (char*)d_ws;
    double*    xm    = (double*)(ws);                    // 256 KB (holds 4096 - xx)
    float*     gsum  = (float*)(ws + 262144);            // 256 B
    float*     gsum2 = (float*)(ws + 262400);            // 256 B
    int*       idx   = (int*)  (ws + 393216);            // 2 MB
    _Float16*  xhT   = (_Float16*)(ws + 2490368);        // 4 MB
    _Float16*  xlT   = (_Float16*)(ws + 6684672);        // 4 MB
    float*     P     = (float*)(ws + 10878976);          // 8 MB
    float*     Q     = (float*)(ws + 19267584);          // 8 MB
    double*    part  = (double*)(ws + 10878976);         // 16 MB, aliases P+Q (dead until k_pq)
    float*     Mx    = (float*)(ws + 2490368);           // 8 MB, aliases xhT+xlT (dead after k_knn)
    float*     Mn    = (float*)(ws + 27656192);          // 8 MB (end ~36 MB, proven size)

    hipMemsetAsync(gsum, 0, 512, stream);
    k_prep  <<<dim3(512),        256, 0, stream>>>(x, xm, xhT, xlT);
    k_knn   <<<dim3(64, 8, 4),   256, 0, stream>>>(x, xm, xhT, xlT, part);
    k_kmerge<<<dim3(128),        256, 0, stream>>>(part, idx);
    k_pq    <<<dim3(512),        256, 0, stream>>>(x, W, P, Q);
    k_stats <<<dim3(256, 8),     256, 0, stream>>>(P, Q, idx, Mx, Mn, gsum, gsum2);
    k_final <<<dim3(64, 8),      256, 0, stream>>>(Mx, Mn, gsum, gsum2, gamma, beta, out);
}

// Round 8
// 450.991 us; speedup vs baseline: 1.1749x; 1.1749x over previous
//
#include <hip/hip_runtime.h>

#define NPTS 4096
#define NCH  64
#define NB   8
#define KNN  16

typedef _Float16 h8 __attribute__((ext_vector_type(8)));
typedef float    f4 __attribute__((ext_vector_type(4)));
typedef unsigned long long ull;

// Bitonic sort 16 doubles DESCENDING (fully unrolled, static indices).
__device__ __forceinline__ void sort16_desc(double* d) {
    #pragma unroll
    for (int k2 = 2; k2 <= 16; k2 <<= 1) {
        #pragma unroll
        for (int j2 = k2 >> 1; j2 > 0; j2 >>= 1) {
            #pragma unroll
            for (int i = 0; i < 16; ++i) {
                int l = i ^ j2;
                if (l > i) {
                    double lo = fmin(d[i], d[l]);
                    double hi = fmax(d[i], d[l]);
                    bool up = ((i & k2) == 0);
                    d[i] = up ? hi : lo;           // descending blocks
                    d[l] = up ? lo : hi;
                }
            }
        }
    }
}

// Bitonic merge: s[16] bitonic (valley) -> ascending. 32 CE.
__device__ __forceinline__ void bmerge16_asc(double* s) {
    #pragma unroll
    for (int j2 = 8; j2 > 0; j2 >>= 1) {
        #pragma unroll
        for (int i = 0; i < 16; ++i) {
            int l = i ^ j2;
            if (l > i) {
                double lo = fmin(s[i], s[l]);
                double hi = fmax(s[i], s[l]);
                s[i] = lo; s[l] = hi;
            }
        }
    }
}

// ---------------- K1: xm = 4096 - sum_c x^2 (f64) + transposed f16 hi/lo ------
__global__ __launch_bounds__(256) void k_prep(const float* __restrict__ x,
                                              double* __restrict__ xm,
                                              _Float16* __restrict__ xhT,
                                              _Float16* __restrict__ xlT) {
    __shared__ float tile[64 * 65];
    const int tid = threadIdx.x;
    const int blk = blockIdx.x;
    const int b = blk >> 6, n0 = (blk & 63) << 6;
    const float* xb = x + (size_t)b * NCH * NPTS;
    for (int i = tid; i < 4096; i += 256) {
        int c = i >> 6, nn = i & 63;
        tile[c * 65 + nn] = xb[(size_t)c * NPTS + n0 + nn];
    }
    __syncthreads();
    if (tid < 64) {
        double a = 0.0;
        #pragma unroll
        for (int c = 0; c < 64; ++c) {
            double v = (double)tile[c * 65 + tid];
            a = fma(v, v, a);
        }
        xm[((size_t)b << 12) + n0 + tid] = 4096.0 - a;
    }
    for (int i = tid; i < 4096; i += 256) {
        int n = i >> 6, c = i & 63;
        float v = tile[c * 65 + n];
        _Float16 h = (_Float16)v;
        _Float16 l = (_Float16)(v - (float)h);
        size_t o = (((size_t)b << 12) + n0 + n) * 64 + c;
        xhT[o] = h;
        xlT[o] = l;
    }
}

// ---------------- K2: KNN top-16, f16-split MFMA, batched bitonic scan --------
// Lane (g,j) of wave w: query q0+16w+j; per tile it owns 16 candidates
// (4 mt x 4 r). Batch: sort-16 desc -> s[i]=fmax(s[i],d[i]) -> bitonic merge.
// Inter-scanner merge via shfl of already-sorted lists. Probe + f64 fallback.
__global__ __launch_bounds__(256) void k_knn(const float* __restrict__ x,
                                             const double* __restrict__ xm,
                                             const _Float16* __restrict__ xhT,
                                             const _Float16* __restrict__ xlT,
                                             int* __restrict__ idx_out) {
    __shared__ int okflag;
    const int tid = threadIdx.x, lane = tid & 63, w = tid >> 6;
    const int g = lane >> 4, j = lane & 15;
    const int b = blockIdx.y, q0 = blockIdx.x * 64;
    const size_t bbase = (size_t)b << 12;
    const _Float16* Hb = xhT + bbase * 64;
    const _Float16* Lb = xlT + bbase * 64;
    const double*  xmb = xm + bbase;
    const float*   xb  = x + (size_t)b * NCH * NPTS;

    const int qcol = q0 + 16 * w + j;
    h8 Bh[2], Bl[2];
    #pragma unroll
    for (int kk = 0; kk < 2; ++kk) {
        size_t o = (size_t)qcol * 64 + kk * 32 + 8 * g;
        Bh[kk] = *(const h8*)(Hb + o);
        Bl[kk] = *(const h8*)(Lb + o);
    }

    if (tid == 0) okflag = 1;
    __syncthreads();

    // ---- asymmetric layout probe (shift-by-1 queries as A) ----
    {
        const int rsh = q0 + 16 * w + ((j + 1) & 15);
        f4 acc = {0.f, 0.f, 0.f, 0.f};
        #pragma unroll
        for (int kk = 0; kk < 2; ++kk) {
            size_t o = (size_t)rsh * 64 + kk * 32 + 8 * g;
            h8 Ah = *(const h8*)(Hb + o);
            h8 Al = *(const h8*)(Lb + o);
            acc = __builtin_amdgcn_mfma_f32_16x16x32_f16(Ah, Bh[kk], acc, 0, 0, 0);
            acc = __builtin_amdgcn_mfma_f32_16x16x32_f16(Ah, Bl[kk], acc, 0, 0, 0);
            acc = __builtin_amdgcn_mfma_f32_16x16x32_f16(Al, Bh[kk], acc, 0, 0, 0);
        }
        bool bad = false;
        #pragma unroll
        for (int rr = 0; rr < 2; ++rr) {
            const int r = rr ? 3 : 0;
            const int urow = q0 + 16 * w + ((4 * g + r + 1) & 15);
            double tgt = 0.0;
            #pragma unroll 4
            for (int c = 0; c < 64; ++c) {
                double av = (double)(float)Hb[(size_t)urow * 64 + c]
                          + (double)(float)Lb[(size_t)urow * 64 + c];
                double bv = (double)(float)Hb[(size_t)qcol * 64 + c]
                          + (double)(float)Lb[(size_t)qcol * 64 + c];
                tgt = fma(av, bv, tgt);
            }
            double got = (double)acc[r];
            if (fabs(got - tgt) > 1e-3 * (1.0 + fabs(tgt))) bad = true;
        }
        if (__any(bad ? 1 : 0)) okflag = 0;   // benign same-value race
    }
    __syncthreads();
    const bool mfma_ok = (okflag != 0);

    double s[16];
    #pragma unroll
    for (int i = 0; i < 16; ++i) s[i] = 0.0;

    for (int t = 0; t < 64; ++t) {
        const int m0 = t * 64;
        double d[16];
        if (mfma_ok) {
            #pragma unroll
            for (int mt = 0; mt < 4; ++mt) {
                const int arow = m0 + 16 * mt + j;
                f4 acc = {0.f, 0.f, 0.f, 0.f};
                #pragma unroll
                for (int kk = 0; kk < 2; ++kk) {
                    size_t o = (size_t)arow * 64 + kk * 32 + 8 * g;
                    h8 Ah = *(const h8*)(Hb + o);
                    h8 Al = *(const h8*)(Lb + o);
                    acc = __builtin_amdgcn_mfma_f32_16x16x32_f16(Ah, Bh[kk], acc, 0, 0, 0);
                    acc = __builtin_amdgcn_mfma_f32_16x16x32_f16(Ah, Bl[kk], acc, 0, 0, 0);
                    acc = __builtin_amdgcn_mfma_f32_16x16x32_f16(Al, Bh[kk], acc, 0, 0, 0);
                }
                const int mbase = m0 + 16 * mt + 4 * g;
                #pragma unroll
                for (int r = 0; r < 4; ++r) {
                    const int m = mbase + r;
                    double pv = fma(2.0, (double)acc[r], xmb[m]);  // 2*dot - xx + 4096
                    ull bits = (((ull)__double_as_longlong(pv)) & 0xFFFFFFFFFFFFF000ULL)
                             | (ull)(4095 - m);
                    d[mt * 4 + r] = __longlong_as_double((long long)bits);
                }
            }
        } else {
            // insurance fallback: exact f64 dots straight from global x
            #pragma unroll
            for (int mt = 0; mt < 4; ++mt) {
                #pragma unroll
                for (int r = 0; r < 4; ++r) {
                    const int m = m0 + 16 * mt + 4 * g + r;
                    double dot = 0.0;
                    for (int c = 0; c < 64; ++c)
                        dot = fma((double)xb[(size_t)c * NPTS + m],
                                  (double)xb[(size_t)c * NPTS + qcol], dot);
                    double pv = fma(2.0, dot, xmb[m]);
                    ull bits = (((ull)__double_as_longlong(pv)) & 0xFFFFFFFFFFFFF000ULL)
                             | (ull)(4095 - m);
                    d[mt * 4 + r] = __longlong_as_double((long long)bits);
                }
            }
        }
        sort16_desc(d);
        #pragma unroll
        for (int i = 0; i < 16; ++i) s[i] = fmax(s[i], d[i]);
        bmerge16_asc(s);
    }

    // ---- in-wave scanner merge (lists are sorted asc): g0<-g2,g1<-g3; g0<-g1
    {
        double d2[16];
        #pragma unroll
        for (int i = 0; i < 16; ++i)
            d2[i] = __shfl(s[15 - i], (lane + 32) & 63, 64);   // partner desc
        if (g < 2) {
            #pragma unroll
            for (int i = 0; i < 16; ++i) s[i] = fmax(s[i], d2[i]);
            bmerge16_asc(s);
        }
        #pragma unroll
        for (int i = 0; i < 16; ++i)
            d2[i] = __shfl(s[15 - i], (lane + 16) & 63, 64);
        if (g == 0) {
            #pragma unroll
            for (int i = 0; i < 16; ++i) s[i] = fmax(s[i], d2[i]);
            // final multiset is correct; order within k irrelevant downstream
            int* op = idx_out + (bbase + (size_t)qcol) * KNN;
            #pragma unroll
            for (int i = 0; i < 16; ++i) {
                int code = (int)((ull)__double_as_longlong(s[i]) & 0xFFFULL);
                op[i] = 4095 - code;
            }
        }
    }
}

// ---------------- K3: P = W1 * x ; Q = (W2 - W1) * x  (both [b][n][o]) --------
__global__ __launch_bounds__(256) void k_pq(const float* __restrict__ x,
                                            const float* __restrict__ W,
                                            float* __restrict__ P,
                                            float* __restrict__ Q) {
    __shared__ __align__(16) float sX[4096];
    __shared__ __align__(16) float sWt[8192];
    const int tid = threadIdx.x;
    const int g0  = blockIdx.x * 64;
    const int b   = g0 >> 12;
    const int n0  = g0 & 4095;
    const float* xb = x + (size_t)b * NCH * NPTS;

    for (int i = tid; i < 8192; i += 256) {
        int c = i >> 7, oc = i & 127;
        float wv;
        if (oc < 64) wv = W[oc * 128 + c];
        else { int o = oc - 64; wv = W[o * 128 + 64 + c] - W[o * 128 + c]; }
        sWt[c * 128 + oc] = wv;
    }
    for (int i = tid; i < 4096; i += 256) {
        int c = i >> 6, m = i & 63;
        sX[i] = xb[(size_t)c * NPTS + n0 + m];
    }
    __syncthreads();

    const int ty = tid >> 4, tx = tid & 15;
    float aP[4][4], aQ[4][4];
    #pragma unroll
    for (int i = 0; i < 4; ++i)
        #pragma unroll
        for (int jj = 0; jj < 4; ++jj) { aP[i][jj] = 0.f; aQ[i][jj] = 0.f; }

    const float4* a4 = (const float4*)sX + ty;
    const float4* p4 = (const float4*)sWt + tx;
    const float4* q4 = (const float4*)sWt + 16 + tx;
    #pragma unroll 8
    for (int kk = 0; kk < 64; ++kk) {
        float4 a  = a4[kk * 16];
        float4 wp = p4[kk * 32];
        float4 wq = q4[kk * 32];
        aP[0][0] = fmaf(a.x, wp.x, aP[0][0]); aP[0][1] = fmaf(a.x, wp.y, aP[0][1]);
        aP[0][2] = fmaf(a.x, wp.z, aP[0][2]); aP[0][3] = fmaf(a.x, wp.w, aP[0][3]);
        aP[1][0] = fmaf(a.y, wp.x, aP[1][0]); aP[1][1] = fmaf(a.y, wp.y, aP[1][1]);
        aP[1][2] = fmaf(a.y, wp.z, aP[1][2]); aP[1][3] = fmaf(a.y, wp.w, aP[1][3]);
        aP[2][0] = fmaf(a.z, wp.x, aP[2][0]); aP[2][1] = fmaf(a.z, wp.y, aP[2][1]);
        aP[2][2] = fmaf(a.z, wp.z, aP[2][2]); aP[2][3] = fmaf(a.z, wp.w, aP[2][3]);
        aP[3][0] = fmaf(a.w, wp.x, aP[3][0]); aP[3][1] = fmaf(a.w, wp.y, aP[3][1]);
        aP[3][2] = fmaf(a.w, wp.z, aP[3][2]); aP[3][3] = fmaf(a.w, wp.w, aP[3][3]);
        aQ[0][0] = fmaf(a.x, wq.x, aQ[0][0]); aQ[0][1] = fmaf(a.x, wq.y, aQ[0][1]);
        aQ[0][2] = fmaf(a.x, wq.z, aQ[0][2]); aQ[0][3] = fmaf(a.x, wq.w, aQ[0][3]);
        aQ[1][0] = fmaf(a.y, wq.x, aQ[1][0]); aQ[1][1] = fmaf(a.y, wq.y, aQ[1][1]);
        aQ[1][2] = fmaf(a.y, wq.z, aQ[1][2]); aQ[1][3] = fmaf(a.y, wq.w, aQ[1][3]);
        aQ[2][0] = fmaf(a.z, wq.x, aQ[2][0]); aQ[2][1] = fmaf(a.z, wq.y, aQ[2][1]);
        aQ[2][2] = fmaf(a.z, wq.z, aQ[2][2]); aQ[2][3] = fmaf(a.z, wq.w, aQ[2][3]);
        aQ[3][0] = fmaf(a.w, wq.x, aQ[3][0]); aQ[3][1] = fmaf(a.w, wq.y, aQ[3][1]);
        aQ[3][2] = fmaf(a.w, wq.z, aQ[3][2]); aQ[3][3] = fmaf(a.w, wq.w, aQ[3][3]);
    }
    #pragma unroll
    for (int i = 0; i < 4; ++i) {
        size_t row = (size_t)(g0 + ty * 4 + i) * 64;
        float4 vp; vp.x = aP[i][0]; vp.y = aP[i][1]; vp.z = aP[i][2]; vp.w = aP[i][3];
        float4 vq; vq.x = aQ[i][0]; vq.y = aQ[i][1]; vq.z = aQ[i][2]; vq.w = aQ[i][3];
        ((float4*)(P + row))[tx] = vp;
        ((float4*)(Q + row))[tx] = vq;
    }
}

// ---------------- K4: gather + max/min over k + global sum/sumsq --------------
__global__ __launch_bounds__(256) void k_stats(const float* __restrict__ P,
                                               const float* __restrict__ Q,
                                               const int* __restrict__ idx,
                                               float* __restrict__ Mx,
                                               float* __restrict__ Mn,
                                               float* __restrict__ gsum,
                                               float* __restrict__ gsum2) {
    const int tid = threadIdx.x;
    const int o = tid & 63, ng = tid >> 6;
    const int b = blockIdx.y;
    const int n0 = blockIdx.x * 16;
    const float* Pb = P + (((size_t)b << 12) * 64);
    float ssum = 0.f, ssq = 0.f;
    for (int jj = 0; jj < 4; ++jj) {
        int n = n0 + ng * 4 + jj;
        size_t base = ((size_t)b << 12) + n;
        float qv = Q[base * 64 + o];
        const int* ip = idx + base * 16;
        float vmax = -3.4e38f, vmin = 3.4e38f;
        #pragma unroll
        for (int k = 0; k < 16; ++k) {
            int m = ip[k];
            float v = Pb[(size_t)m * 64 + o] + qv;
            vmax = fmaxf(vmax, v);
            vmin = fminf(vmin, v);
            ssum += v;
            ssq  = fmaf(v, v, ssq);
        }
        Mx[base * 64 + o] = vmax;
        Mn[base * 64 + o] = vmin;
    }
    __shared__ float red[8][64];
    red[ng][o] = ssum;
    red[ng + 4][o] = ssq;
    __syncthreads();
    if (tid < 64) {
        float ss  = red[0][o] + red[1][o] + red[2][o] + red[3][o];
        float ss2 = red[4][o] + red[5][o] + red[6][o] + red[7][o];
        atomicAdd(&gsum[o], ss);
        atomicAdd(&gsum2[o], ss2);
    }
}

// ---------------- K5: BN + LeakyReLU + transpose to [b][o][n] -----------------
__global__ __launch_bounds__(256) void k_final(const float* __restrict__ Mx,
                                               const float* __restrict__ Mn,
                                               const float* __restrict__ gsum,
                                               const float* __restrict__ gsum2,
                                               const float* __restrict__ gamma,
                                               const float* __restrict__ beta,
                                               float* __restrict__ out) {
    __shared__ float tX[64 * 65], tN[64 * 65];
    const int tid = threadIdx.x;
    const int b = blockIdx.y;
    const int n0 = blockIdx.x * 64;
    size_t base = ((size_t)b << 12) + n0;
    for (int i = tid; i < 4096; i += 256) {
        int nl = i >> 6, o = i & 63;
        tX[nl * 65 + o] = Mx[(base + nl) * 64 + o];
        tN[nl * 65 + o] = Mn[(base + nl) * 64 + o];
    }
    __syncthreads();
    const int lane = tid & 63, wv = tid >> 6;
    const float inv = 1.0f / 524288.0f;
    for (int oo = 0; oo < 16; ++oo) {
        int o = wv * 16 + oo;
        float mean = gsum[o] * inv;
        float var  = gsum2[o] * inv - mean * mean;
        float scv  = gamma[o] * rsqrtf(var + 1e-5f);
        float bsv  = beta[o] - mean * scv;
        float M = (scv >= 0.f) ? tX[lane * 65 + o] : tN[lane * 65 + o];
        float v = fmaf(scv, M, bsv);
        out[((size_t)b * 64 + o) * 4096 + n0 + lane] = (v >= 0.f) ? v : 0.2f * v;
    }
}

extern "C" void kernel_launch(void* const* d_in, const int* in_sizes, int n_in,
                              void* d_out, int out_size, void* d_ws, size_t ws_size,
                              hipStream_t stream) {
    const float* x     = (const float*)d_in[0];
    const float* W     = (const float*)d_in[1];
    const float* gamma = (const float*)d_in[2];
    const float* beta  = (const float*)d_in[3];
    float* out = (float*)d_out;

    char* ws = (char*)d_ws;
    double*    xm    = (double*)(ws);                    // 256 KB (holds 4096 - xx)
    float*     gsum  = (float*)(ws + 262144);            // 256 B
    float*     gsum2 = (float*)(ws + 262400);            // 256 B
    int*       idx   = (int*)  (ws + 393216);            // 2 MB
    _Float16*  xhT   = (_Float16*)(ws + 2490368);        // 4 MB
    _Float16*  xlT   = (_Float16*)(ws + 6684672);        // 4 MB
    float*     P     = (float*)(ws + 10878976);          // 8 MB
    float*     Q     = (float*)(ws + 19267584);          // 8 MB
    float*     Mx    = (float*)(ws + 2490368);           // 8 MB, aliases xhT+xlT (dead after k_knn)
    float*     Mn    = (float*)(ws + 27656192);          // 8 MB (end ~36 MB, proven size)

    hipMemsetAsync(gsum, 0, 512, stream);
    k_prep  <<<dim3(512),      256, 0, stream>>>(x, xm, xhT, xlT);
    k_knn   <<<dim3(64, 8),    256, 0, stream>>>(x, xm, xhT, xlT, idx);
    k_pq    <<<dim3(512),      256, 0, stream>>>(x, W, P, Q);
    k_stats <<<dim3(256, 8),   256, 0, stream>>>(P, Q, idx, Mx, Mn, gsum, gsum2);
    k_final <<<dim3(64, 8),    256, 0, stream>>>(Mx, Mn, gsum, gsum2, gamma, beta, out);
}